// Round 10
// baseline (67044.183 us; speedup 1.0000x reference)
//
#include <hip/hip_runtime.h>
#include <hip/hip_bf16.h>
#include <math.h>
#include <type_traits>

#define BB 512
#define HH 512
#define TT 1024

typedef __bf16 bf16;
typedef __bf16 bf16x8 __attribute__((ext_vector_type(8)));
typedef float f32x4 __attribute__((ext_vector_type(4)));
typedef unsigned long long ull;
typedef ull ull2 __attribute__((ext_vector_type(2)));

#define SENT 0x7FC07FC07FC07FC0ULL   // 4x bf16 NaN — h = so*tanh(c) is never NaN
#define HMD  (3*512*1024)            // HL -> HM pointer delta

// ---------------- ws layout (bytes) ----------------
// WcT : [2048][512] bf16 @ 0      (2 MB)  folded: Whh + Wfc ⊗ Wih
// biasC: [2048] f32      @ 2 MB   (8 KB)
// HL0/1/2: 3 x 512 KB rotating h buffers, L2-local copy (sc0 path)
// HM0/1/2: 3 x 512 KB rotating h buffers, MALL copy (sc0 sc1 path)
// cnt : [8] int   per-XCD claim counters (SYSTEM-scope RMW only!)
// bm  : [8] u32   role bitmap (SYSTEM-scope RMW only!)
// status: [256] int  1=clean (claimed on home XCD), 2=displaced
#define WT_OFF 0
#define BC_OFF (2*1024*1024)
#define HL_OFF (BC_OFF + 8192)
#define HM_OFF (HL_OFF + HMD)
#define CN_OFF (HM_OFF + HMD)
#define BM_OFF (CN_OFF + 64)
#define ST_OFF (BM_OFF + 64)

__global__ void prep_weights(const float* __restrict__ Whh, const float* __restrict__ Wih,
                             const float* __restrict__ bih, const float* __restrict__ bhh,
                             const float* __restrict__ Wfc, const float* __restrict__ bfc,
                             bf16* __restrict__ WcT, float* __restrict__ biasC) {
    int col = blockIdx.x;                 // 0..2047
    float wih = Wih[col];
    for (int k = threadIdx.x; k < HH; k += blockDim.x)
        WcT[col * HH + k] = (bf16)(Whh[col * HH + k] + Wfc[k] * wih);
    if (threadIdx.x == 0) biasC[col] = bih[col] + bhh[col] + bfc[0] * wih;
}

__global__ void prep_state(const float* __restrict__ h, char* __restrict__ ws) {
    int i = blockIdx.x * blockDim.x + threadIdx.x;
    unsigned short* l0 = (unsigned short*)(ws + HL_OFF);
    unsigned short* m0 = (unsigned short*)(ws + HM_OFF);
    if (i < BB * HH) {
        bf16 v = (bf16)h[i];
        unsigned short u = *(unsigned short*)&v;
        l0[i] = u;                        m0[i] = u;
        l0[i + 262144] = 0x7FC0;          m0[i + 262144] = 0x7FC0;   // buf1
        l0[i + 524288] = 0x7FC0;          m0[i + 524288] = 0x7FC0;   // buf2
    }
    if (i < 256) ((int*)(ws + ST_OFF))[i] = 0;
    if (i < 8)  { ((int*)(ws + CN_OFF))[i] = 0; ((unsigned*)(ws + BM_OFF))[i] = 0; }
}

__device__ __forceinline__ float tanh_fast(float x) {
    float ax = fabsf(x);
    float e = __expf(-2.f * ax);
    float r = (1.f - e) / (1.f + e);
    return copysignf(r, x);
}
__device__ __forceinline__ float sigmoid_fast(float x) {
    return 1.f / (1.f + __expf(-x));
}
__device__ __forceinline__ bool has_sent(ull v) {
    ull y = v ^ SENT;
    return ((y - 0x0001000100010001ULL) & ~y & 0x8000800080008000ULL) != 0ULL;
}
__device__ __forceinline__ bool has_sent2(ull2 v) {
    return has_sent(v.x) | has_sent(v.y);
}

// Persistent LSTM. Roles claimed per measured XCC_ID with SYSTEM-scope RMWs
// (plain atomics are per-XCD-L2 and NOT cross-XCD coherent — the r7/r8 hang).
// 1 wg/CU forced by a static, volatile-touched 45KB LDS pad => exactly 32
// wgs/XCD => every bt-group co-XCD by construction => h-exchange via sc0-only
// loads/stores through the SHARED per-XCD L2 (safe: producer stores update
// the same L2 line the consumer polls). Dual-store keeps a MALL copy
// (sc0 sc1) so any displaced/anomalous consumer falls back to the proven
// round-9 protocol. NaN-sentinel 3-buffer dataflow; no per-step RMW/fences.
__global__ __launch_bounds__(256, 1) void lstm_persist(
    const bf16* __restrict__ WcT,     // [2048][512] bf16 (folded)
    const float* __restrict__ biasC,  // [2048]
    const float* __restrict__ Wih,    // [2048]
    const float* __restrict__ Wfc,    // [512]
    const float* __restrict__ bfc,    // [1]
    const float* __restrict__ c0,     // [512*512] f32
    char* __restrict__ ws,            // workspace base
    float* __restrict__ out)          // [512][1024]
{
    __shared__ char occpad[46080];                 // static pad: 1 wg/CU
    __shared__ __align__(16) bf16 Alds[32 * 512];  // XOR-swizzled h tile (32 KB)
    __shared__ float xls[32];                      // step-0 correction per row
    __shared__ float WfcLDS[512];
    __shared__ bf16 hrep[32][40];                  // h repack for coalesced stores
    __shared__ int roleLDS;
    __shared__ int dmLDS;

    const int tid  = threadIdx.x;
    const int wave = tid >> 6;
    const int lane = tid & 63;
    const int l15  = lane & 15;
    const int hi   = lane >> 4;

    ((volatile char*)occpad)[tid] = 0;   // force pad allocation (occupancy!)

    int* cnt    = (int*)(ws + CN_OFF);
    unsigned* bm = (unsigned*)(ws + BM_OFF);
    int* status = (int*)(ws + ST_OFF);
    char* hl    = ws + HL_OFF;

    // ---- claim a unique role (SYSTEM-scope RMWs -> MALL-coherent) ----
    if (tid == 0) {
        unsigned xid;
        asm volatile("s_getreg_b32 %0, hwreg(HW_REG_XCC_ID)" : "=s"(xid));
        xid &= 7;
        int slot = __hip_atomic_fetch_add(&cnt[xid], 1, __ATOMIC_RELAXED,
                                          __HIP_MEMORY_SCOPE_SYSTEM);
        int role = -1, disp = 0;
        if (slot < 32) {
            unsigned old = __hip_atomic_fetch_or(&bm[xid], 1u << slot,
                                                 __ATOMIC_RELAXED, __HIP_MEMORY_SCOPE_SYSTEM);
            if (!(old & (1u << slot))) role = (int)xid * 32 + slot;
        }
        if (role < 0) {                          // anomalous world: scan bitmap
            disp = 1;
            for (;;) {
                bool got = false;
                for (int w = 0; w < 8 && !got; ++w) {
                    unsigned cur = __hip_atomic_load(&bm[w], __ATOMIC_RELAXED,
                                                     __HIP_MEMORY_SCOPE_SYSTEM);
                    if (cur != 0xFFFFFFFFu) {
                        int b = __ffs((int)~cur) - 1;
                        unsigned old = __hip_atomic_fetch_or(&bm[w], 1u << b,
                                            __ATOMIC_RELAXED, __HIP_MEMORY_SCOPE_SYSTEM);
                        if (!(old & (1u << b))) { role = w * 32 + b; got = true; }
                    }
                }
                if (got) break;
                __builtin_amdgcn_s_sleep(1);
            }
        }
        __hip_atomic_store(&status[role], 1 + disp, __ATOMIC_RELAXED,
                           __HIP_MEMORY_SCOPE_SYSTEM);
        roleLDS = role | (disp << 16);
    }
    __syncthreads();
    const int role = roleLDS & 0xFFFF;
    const int selfdisp = roleLDS >> 16;
    const int bt = (role >> 5) * 2 + ((role >> 4) & 1);   // home XCD * 2 + half
    const int hs = role & 15;

    WfcLDS[tid] = Wfc[tid];
    WfcLDS[tid + 256] = Wfc[tid + 256];

    // ---- preload folded weights into registers (overlaps peers' publish) ----
    bf16x8 breg[2][16];
    float biasr[2], wihr[2];
    #pragma unroll
    for (int nt = 0; nt < 2; ++nt) {
        int gcol = (nt * 2 + (l15 >> 3)) * HH + hs * 32 + wave * 8 + (l15 & 7);
        const bf16* wp = WcT + (size_t)gcol * HH + hi * 8;
        #pragma unroll
        for (int kk = 0; kk < 16; ++kk)
            breg[nt][kk] = *(const bf16x8*)(wp + kk * 32);
        biasr[nt] = biasC[gcol];
        wihr[nt]  = Wih[gcol];
    }
    const bool lo = (l15 < 8);
    float p0 = __shfl_xor(biasr[0], 8), p1 = __shfl_xor(biasr[1], 8);
    const float bI = lo ? biasr[0] : p0, bF = lo ? p0 : biasr[0];
    const float bG = lo ? biasr[1] : p1, bO = lo ? p1 : biasr[1];
    p0 = __shfl_xor(wihr[0], 8); p1 = __shfl_xor(wihr[1], 8);
    const float wI = lo ? wihr[0] : p0, wF = lo ? p0 : wihr[0];
    const float wG = lo ? wihr[1] : p1, wO = lo ? p1 : wihr[1];

    const int mymt = lo ? 0 : 1;
    const int jcol = wave * 8 + (l15 & 7);    // col within slice (0..31)
    const int jloc = hs * 32 + jcol;
    float creg[4];
    #pragma unroll
    for (int r = 0; r < 4; ++r) {
        int brow = bt * 32 + mymt * 16 + hi * 4 + r;
        creg[r] = c0[(size_t)brow * HH + jloc];
    }
    const float bfcv = bfc[0];

    // ---- group mode: clean iff self + all 16 members claimed on home XCD ----
    if (tid == 0) {
        int base = role & ~15;
        int dirty = selfdisp;
        for (int m = 0; m < 16; ++m) {
            int v;
            while ((v = __hip_atomic_load(&status[base + m], __ATOMIC_RELAXED,
                                          __HIP_MEMORY_SCOPE_SYSTEM)) == 0)
                __builtin_amdgcn_s_sleep(1);
            dirty |= (v >> 1);
        }
        dmLDS = dirty;
    }

    const int swz = l15 & 7;
    const int row = tid >> 3;                 // pointwise/store row 0..31
    const int seg = tid & 7;
    const int r7  = row & 7;

    // load base (lane-contiguous): wave w covers rows w*8..w*8+8, lane reads
    // 16B at row*1024 + lane*16; rows j=0..3 via base, j=4..7 via base+4096.
    const size_t grp = ((size_t)(bt * 32 + wave * 8)) * 1024 + (size_t)lane * 16;
    // store addr: 8B at (bt*32+row)*1024 + hs*64 + seg*8
    const size_t sto = ((size_t)(bt * 32 + row)) * 1024 + (size_t)hs * 64 + (size_t)seg * 8;

    char* laA = hl + grp;                  // buf[s%3]     (read A_s), HL copy
    char* laB = hl + 512 * 1024 + grp;
    char* laC = hl + 1024 * 1024 + grp;
    char* stB = hl + 512 * 1024 + sto;     // buf[(s+1)%3] (write A_{s+1})
    char* stC = hl + 1024 * 1024 + sto;    // buf[(s+2)%3] (clear-behind)
    char* stA = hl + sto;

    char* aldsW = (char*)Alds + wave * 8 * 1024;   // this wave's 8 LDS rows

    __syncthreads();   // WfcLDS + dmLDS ready
    const int dmode = dmLDS;

    auto run = [&](auto dm_c) {
        constexpr bool DM = decltype(dm_c)::value;
        for (int s = 0; s <= TT; ++s) {
            if (s == TT && hs != 0) break;  // only hs==0 needs the final tile

            // 1. stage A_s tile. CLEAN: poll HL via sc0 (shared per-XCD L2,
            //    ~0.3us RT), escalate to the MALL copy after 64 misses
            //    (hang-proof). DIRTY: poll HM via sc0 sc1 (r9-proven).
            {
                char* blo = DM ? (laA + HMD) : laA;
                char* bhi = blo + 4096;
                unsigned pend = 0xFFu;
                int spins = 0;
                ull2 q0, q1, q2, q3, q4, q5, q6, q7;
                for (;;) {
                    if constexpr (!DM) {
                        if (pend & 0x01u) asm volatile("global_load_dwordx4 %0, %1, off sc0"             : "=v"(q0) : "v"(blo) : "memory");
                        if (pend & 0x02u) asm volatile("global_load_dwordx4 %0, %1, off offset:1024 sc0" : "=v"(q1) : "v"(blo) : "memory");
                        if (pend & 0x04u) asm volatile("global_load_dwordx4 %0, %1, off offset:2048 sc0" : "=v"(q2) : "v"(blo) : "memory");
                        if (pend & 0x08u) asm volatile("global_load_dwordx4 %0, %1, off offset:3072 sc0" : "=v"(q3) : "v"(blo) : "memory");
                        if (pend & 0x10u) asm volatile("global_load_dwordx4 %0, %1, off sc0"             : "=v"(q4) : "v"(bhi) : "memory");
                        if (pend & 0x20u) asm volatile("global_load_dwordx4 %0, %1, off offset:1024 sc0" : "=v"(q5) : "v"(bhi) : "memory");
                        if (pend & 0x40u) asm volatile("global_load_dwordx4 %0, %1, off offset:2048 sc0" : "=v"(q6) : "v"(bhi) : "memory");
                        if (pend & 0x80u) asm volatile("global_load_dwordx4 %0, %1, off offset:3072 sc0" : "=v"(q7) : "v"(bhi) : "memory");
                    } else {
                        if (pend & 0x01u) asm volatile("global_load_dwordx4 %0, %1, off sc0 sc1"             : "=v"(q0) : "v"(blo) : "memory");
                        if (pend & 0x02u) asm volatile("global_load_dwordx4 %0, %1, off offset:1024 sc0 sc1" : "=v"(q1) : "v"(blo) : "memory");
                        if (pend & 0x04u) asm volatile("global_load_dwordx4 %0, %1, off offset:2048 sc0 sc1" : "=v"(q2) : "v"(blo) : "memory");
                        if (pend & 0x08u) asm volatile("global_load_dwordx4 %0, %1, off offset:3072 sc0 sc1" : "=v"(q3) : "v"(blo) : "memory");
                        if (pend & 0x10u) asm volatile("global_load_dwordx4 %0, %1, off sc0 sc1"             : "=v"(q4) : "v"(bhi) : "memory");
                        if (pend & 0x20u) asm volatile("global_load_dwordx4 %0, %1, off offset:1024 sc0 sc1" : "=v"(q5) : "v"(bhi) : "memory");
                        if (pend & 0x40u) asm volatile("global_load_dwordx4 %0, %1, off offset:2048 sc0 sc1" : "=v"(q6) : "v"(bhi) : "memory");
                        if (pend & 0x80u) asm volatile("global_load_dwordx4 %0, %1, off offset:3072 sc0 sc1" : "=v"(q7) : "v"(bhi) : "memory");
                    }
                    asm volatile("s_waitcnt vmcnt(0)" ::: "memory");
                    __builtin_amdgcn_sched_barrier(0);
#define ACCEPT(J, QQ)                                                          \
                    if ((pend & (1u << J)) && !has_sent2(QQ)) {                \
                        *(ull2*)(aldsW + J * 1024 + ((lane ^ J) << 4)) = QQ;   \
                        pend &= ~(1u << J);                                    \
                    }
                    ACCEPT(0, q0) ACCEPT(1, q1) ACCEPT(2, q2) ACCEPT(3, q3)
                    ACCEPT(4, q4) ACCEPT(5, q5) ACCEPT(6, q6) ACCEPT(7, q7)

                    if constexpr (!DM) {
                        // escalation: after 64 misses also poll the MALL copy
                        if (pend && ++spins > 64) {
                            char* mlo = laA + HMD;
                            char* mhi = mlo + 4096;
                            if (pend & 0x01u) asm volatile("global_load_dwordx4 %0, %1, off sc0 sc1"             : "=v"(q0) : "v"(mlo) : "memory");
                            if (pend & 0x02u) asm volatile("global_load_dwordx4 %0, %1, off offset:1024 sc0 sc1" : "=v"(q1) : "v"(mlo) : "memory");
                            if (pend & 0x04u) asm volatile("global_load_dwordx4 %0, %1, off offset:2048 sc0 sc1" : "=v"(q2) : "v"(mlo) : "memory");
                            if (pend & 0x08u) asm volatile("global_load_dwordx4 %0, %1, off offset:3072 sc0 sc1" : "=v"(q3) : "v"(mlo) : "memory");
                            if (pend & 0x10u) asm volatile("global_load_dwordx4 %0, %1, off sc0 sc1"             : "=v"(q4) : "v"(mhi) : "memory");
                            if (pend & 0x20u) asm volatile("global_load_dwordx4 %0, %1, off offset:1024 sc0 sc1" : "=v"(q5) : "v"(mhi) : "memory");
                            if (pend & 0x40u) asm volatile("global_load_dwordx4 %0, %1, off offset:2048 sc0 sc1" : "=v"(q6) : "v"(mhi) : "memory");
                            if (pend & 0x80u) asm volatile("global_load_dwordx4 %0, %1, off offset:3072 sc0 sc1" : "=v"(q7) : "v"(mhi) : "memory");
                            asm volatile("s_waitcnt vmcnt(0)" ::: "memory");
                            __builtin_amdgcn_sched_barrier(0);
                            ACCEPT(0, q0) ACCEPT(1, q1) ACCEPT(2, q2) ACCEPT(3, q3)
                            ACCEPT(4, q4) ACCEPT(5, q5) ACCEPT(6, q6) ACCEPT(7, q7)
                        }
                    }
#undef ACCEPT
                    if (pend == 0) break;
                    __builtin_amdgcn_s_sleep(1);
                }
            }
            __syncthreads();   // full A_s staged => group finished iter s-1

            // 2. clear-behind: sentinel my granule in buf[(s+2)%3], BOTH copies
            {
                ull sv = SENT;
                asm volatile(
                    "global_store_dwordx2 %0, %2, off sc0\n\t"
                    "global_store_dwordx2 %1, %2, off sc0 sc1"
                    :: "v"(stC), "v"(stC + HMD), "v"(sv) : "memory");
            }

            // 3. FC at s==0 (xls correction) and s==TT (final y), pre-MFMA
            if (s == 0 || s == TT) {
                float xacc = 0.f;
                const bf16* arow = Alds + row * 512;
                #pragma unroll
                for (int u = 0; u < 8; ++u) {
                    int cc = seg * 8 + u;
                    bf16x8 v = *(const bf16x8*)(arow + ((cc ^ r7) << 3));
                    const float* wv = WfcLDS + cc * 8;
                    #pragma unroll
                    for (int e = 0; e < 8; ++e) xacc += (float)v[e] * wv[e];
                }
                xacc += __shfl_xor(xacc, 1);
                xacc += __shfl_xor(xacc, 2);
                xacc += __shfl_xor(xacc, 4);
                xacc += bfcv;
                if (seg == 0) {
                    xls[row] = xacc;
                    if (s == TT)
                        out[((size_t)(bt * 32 + row)) * TT + (TT - 1)] = xacc;
                }
            }
            if (s == TT) break;             // epilogue done

            // 4. MFMA: [32,512] @ [512, 32 B-rows]
            f32x4 acc[2][2];
            #pragma unroll
            for (int i = 0; i < 2; ++i)
                #pragma unroll
                for (int j = 0; j < 2; ++j) acc[i][j] = (f32x4)0.f;

            #pragma unroll
            for (int kk = 0; kk < 16; ++kk) {
                int ch = ((hi + 4 * kk) ^ swz) << 3;
                bf16x8 a0 = *(const bf16x8*)(Alds + l15 * 512 + ch);
                bf16x8 a1 = *(const bf16x8*)(Alds + (l15 + 16) * 512 + ch);
                acc[0][0] = __builtin_amdgcn_mfma_f32_16x16x32_bf16(a0, breg[0][kk], acc[0][0], 0, 0, 0);
                acc[0][1] = __builtin_amdgcn_mfma_f32_16x16x32_bf16(a0, breg[1][kk], acc[0][1], 0, 0, 0);
                acc[1][0] = __builtin_amdgcn_mfma_f32_16x16x32_bf16(a1, breg[0][kk], acc[1][0], 0, 0, 0);
                acc[1][1] = __builtin_amdgcn_mfma_f32_16x16x32_bf16(a1, breg[1][kk], acc[1][1], 0, 0, 0);
            }

            if (s == 0) __syncthreads();   // xls visible for the correction

            // 5. pointwise cell update (folded weights include x-feedback;
            //    s==0 subtracts the x0c*Wih correction since x_0 = 0)
            #pragma unroll
            for (int r = 0; r < 4; ++r) {
                float send0 = lo ? acc[1][0][r] : acc[0][0][r];
                float send1 = lo ? acc[1][1][r] : acc[0][1][r];
                float recv0 = __shfl_xor(send0, 8);
                float recv1 = __shfl_xor(send1, 8);
                float own0  = lo ? acc[0][0][r] : acc[1][0][r];
                float own1  = lo ? acc[0][1][r] : acc[1][1][r];
                int  lrow = mymt * 16 + hi * 4 + r;
                float xc = (s == 0) ? xls[lrow] : 0.f;
                float xi = (lo ? own0 : recv0) + bI - xc * wI;
                float xf = (lo ? recv0 : own0) + bF - xc * wF;
                float xg = (lo ? own1 : recv1) + bG - xc * wG;
                float xo = (lo ? recv1 : own1) + bO - xc * wO;
                float si = sigmoid_fast(xi), sf = sigmoid_fast(xf), so = sigmoid_fast(xo);
                float tg = tanh_fast(xg);
                float cn = sf * creg[r] + si * tg;
                creg[r] = cn;
                hrep[lrow][jcol] = (bf16)(so * tanh_fast(cn));
            }
            __syncthreads();   // hrep complete; Alds reads finished

            // 6. store A_{s+1} granule, BOTH copies. vmcnt(0) first: my
            //    sentinel clears of this same granule (iter s-1) drained
            //    before the data stores issue (same thread, same address).
            {
                ull val = *(const ull*)&hrep[row][seg * 4];
                asm volatile(
                    "s_waitcnt vmcnt(0)\n\t"
                    "global_store_dwordx2 %0, %2, off sc0\n\t"
                    "global_store_dwordx2 %1, %2, off sc0 sc1"
                    :: "v"(stB), "v"(stB + HMD), "v"(val) : "memory");
            }

            // 7. y-output FC for hs==0, AFTER the h store (off critical path)
            if (hs == 0 && s > 0) {
                float xacc = 0.f;
                const bf16* arow = Alds + row * 512;
                #pragma unroll
                for (int u = 0; u < 8; ++u) {
                    int cc = seg * 8 + u;
                    bf16x8 v = *(const bf16x8*)(arow + ((cc ^ r7) << 3));
                    const float* wv = WfcLDS + cc * 8;
                    #pragma unroll
                    for (int e = 0; e < 8; ++e) xacc += (float)v[e] * wv[e];
                }
                xacc += __shfl_xor(xacc, 1);
                xacc += __shfl_xor(xacc, 2);
                xacc += __shfl_xor(xacc, 4);
                if (seg == 0)
                    out[((size_t)(bt * 32 + row)) * TT + (s - 1)] = xacc + bfcv;
            }

            // rotate buffers: (A,B,C) <- (B,C,A)
            char* t;
            t = laA; laA = laB; laB = laC; laC = t;
            t = stA; stA = stB; stB = stC; stC = t;
        }
    };

    if (dmode) run(std::integral_constant<bool, true>{});
    else       run(std::integral_constant<bool, false>{});
}

extern "C" void kernel_launch(void* const* d_in, const int* in_sizes, int n_in,
                              void* d_out, int out_size, void* d_ws, size_t ws_size,
                              hipStream_t stream) {
    const float* h   = (const float*)d_in[0];
    const float* c   = (const float*)d_in[1];
    const float* Wih = (const float*)d_in[2];
    const float* Whh = (const float*)d_in[3];
    const float* bih = (const float*)d_in[4];
    const float* bhh = (const float*)d_in[5];
    const float* Wfc = (const float*)d_in[6];
    const float* bfc = (const float*)d_in[7];
    float* out = (float*)d_out;

    char* ws = (char*)d_ws;
    bf16*  WcT   = (bf16*)(ws + WT_OFF);
    float* biasC = (float*)(ws + BC_OFF);

    prep_weights<<<2048, 256, 0, stream>>>(Whh, Wih, bih, bhh, Wfc, bfc, WcT, biasC);
    prep_state<<<1024, 256, 0, stream>>>(h, ws);
    lstm_persist<<<256, 256, 0, stream>>>(WcT, biasC, Wih, Wfc, bfc, c, ws, out);
}

// Round 11
// 6205.699 us; speedup vs baseline: 10.8036x; 10.8036x over previous
//
#include <hip/hip_runtime.h>
#include <hip/hip_bf16.h>
#include <math.h>

#define BB 512
#define HH 512
#define TT 1024

typedef __bf16 bf16;
typedef __bf16 bf16x8 __attribute__((ext_vector_type(8)));
typedef float f32x4 __attribute__((ext_vector_type(4)));
typedef unsigned long long ull;
typedef ull ull2 __attribute__((ext_vector_type(2)));

#define SENT 0x7FC07FC07FC07FC0ULL   // 4x bf16 NaN — h = so*tanh(c) is never NaN

// ---------------- ws layout (bytes) ----------------
// WcT : [2048][512] bf16 @ 0      (2 MB)  folded: Whh + Wfc ⊗ Wih
// biasC: [2048] f32      @ 2 MB   (8 KB)
// hb0/1/2: [512][512] bf16 rotating h buffers (3 x 512 KB)
#define WT_OFF 0
#define BC_OFF (2*1024*1024)
#define H0_OFF (BC_OFF + 8192)

__global__ void prep_weights(const float* __restrict__ Whh, const float* __restrict__ Wih,
                             const float* __restrict__ bih, const float* __restrict__ bhh,
                             const float* __restrict__ Wfc, const float* __restrict__ bfc,
                             bf16* __restrict__ WcT, float* __restrict__ biasC) {
    int col = blockIdx.x;                 // 0..2047
    float wih = Wih[col];
    for (int k = threadIdx.x; k < HH; k += blockDim.x)
        WcT[col * HH + k] = (bf16)(Whh[col * HH + k] + Wfc[k] * wih);
    if (threadIdx.x == 0) biasC[col] = bih[col] + bhh[col] + bfc[0] * wih;
}

__global__ void prep_state(const float* __restrict__ h, bf16* __restrict__ h0buf,
                           unsigned short* __restrict__ h1buf,
                           unsigned short* __restrict__ h2buf) {
    int i = blockIdx.x * blockDim.x + threadIdx.x;
    if (i < BB * HH) {
        h0buf[i] = (bf16)h[i];
        h1buf[i] = 0x7FC0;    // sentinel
        h2buf[i] = 0x7FC0;
    }
}

__device__ __forceinline__ float tanh_fast(float x) {
    float ax = fabsf(x);
    float e = __expf(-2.f * ax);
    float r = (1.f - e) / (1.f + e);
    return copysignf(r, x);
}
__device__ __forceinline__ float sigmoid_fast(float x) {
    return 1.f / (1.f + __expf(-x));
}
__device__ __forceinline__ bool has_sent(ull v) {
    ull y = v ^ SENT;
    return ((y - 0x0001000100010001ULL) & ~y & 0x8000800080008000ULL) != 0ULL;
}
__device__ __forceinline__ bool has_sent2(ull2 v) {
    return has_sent(v.x) | has_sent(v.y);
}

// Persistent LSTM, round-9 protocol (NaN-sentinel, 3 rotating buffers,
// clear-behind, MALL-only sc0 sc1 exchange — the only validated inter-wg
// path), now 2-way batch-stream multiplexed: B=512 as 32 tiles of 16 rows;
// wg (bt,hs) alternates tile bt (stream0) and bt+16 (stream1) each step, so
// one stream's MALL store->poll latency hides under the other's compute.
// Weight VGPRs shared across slots. No flags, no RMW, no cache maintenance.
__global__ __launch_bounds__(256, 1) void lstm_persist(
    const bf16* __restrict__ WcT,     // [2048][512] bf16 (folded)
    const float* __restrict__ biasC,  // [2048]
    const float* __restrict__ Wih,    // [2048]
    const float* __restrict__ Wfc,    // [512]
    const float* __restrict__ bfc,    // [1]
    const float* __restrict__ c0,     // [512*512] f32
    char* __restrict__ hbase,         // 3 x 512KB rotating buffers
    float* __restrict__ out)          // [512][1024]
{
    __shared__ __align__(16) char Alds[16 * 1024];   // swizzled 16x512 bf16 tile
    __shared__ float xls[16];                        // step-0 correction per row
    __shared__ float WfcLDS[512];
    __shared__ __align__(8) bf16 hrep[16][40];       // h repack (80B row stride)

    const int tid  = threadIdx.x;
    const int wave = tid >> 6;
    const int lane = tid & 63;
    const int l15  = lane & 15;
    const int hi   = lane >> 4;
    const int bt   = blockIdx.x & 15;         // tile role within stream
    const int hs   = blockIdx.x >> 4;         // hidden slice 0..15

    WfcLDS[tid] = Wfc[tid];
    WfcLDS[tid + 256] = Wfc[tid + 256];

    // ---- preload folded weights into registers (shared by both slots) ----
    bf16x8 breg[2][16];
    float biasr[2], wihr[2];
    #pragma unroll
    for (int nt = 0; nt < 2; ++nt) {
        int gcol = (nt * 2 + (l15 >> 3)) * HH + hs * 32 + wave * 8 + (l15 & 7);
        const bf16* wp = WcT + (size_t)gcol * HH + hi * 8;
        #pragma unroll
        for (int kk = 0; kk < 16; ++kk)
            breg[nt][kk] = *(const bf16x8*)(wp + kk * 32);
        biasr[nt] = biasC[gcol];
        wihr[nt]  = Wih[gcol];
    }
    const bool lo = (l15 < 8);
    float p0 = __shfl_xor(biasr[0], 8), p1 = __shfl_xor(biasr[1], 8);
    const float bI = lo ? biasr[0] : p0, bF = lo ? p0 : biasr[0];
    const float bG = lo ? biasr[1] : p1, bO = lo ? p1 : biasr[1];
    p0 = __shfl_xor(wihr[0], 8); p1 = __shfl_xor(wihr[1], 8);
    const float wI = lo ? wihr[0] : p0, wF = lo ? p0 : wihr[0];
    const float wG = lo ? wihr[1] : p1, wO = lo ? p1 : wihr[1];

    const int jcol = wave * 8 + (l15 & 7);    // col within slice (0..31)
    const int jloc = hs * 32 + jcol;
    // c-state: lo lanes own rows hi*4+r of their slot's tile, col jloc
    float cregA[4], cregB[4];
    #pragma unroll
    for (int r = 0; r < 4; ++r) {
        cregA[r] = c0[(size_t)((bt     ) * 16 + hi * 4 + r) * HH + jloc];
        cregB[r] = c0[(size_t)((bt + 16) * 16 + hi * 4 + r) * HH + jloc];
    }
    const float bfcv = bfc[0];

    const int srow = (tid & 127) >> 3;        // store row 0..15 (tid<128)
    const int seg  = tid & 7;
    const bool doSt = (tid < 128);

    // byte offsets within a buffer
    const size_t ldOff0 = (size_t)((bt     ) * 16 + wave * 4) * 1024 + (size_t)lane * 16;
    const size_t ldOff1 = (size_t)((bt + 16) * 16 + wave * 4) * 1024 + (size_t)lane * 16;
    const size_t stOff0 = (size_t)((bt     ) * 16 + srow) * 1024 + (size_t)hs * 64 + seg * 8;
    const size_t stOff1 = (size_t)((bt + 16) * 16 + srow) * 1024 + (size_t)hs * 64 + seg * 8;

    char* bA = hbase;                  // buf[s%3]     (read A_s)
    char* bB = hbase + 512 * 1024;     // buf[(s+1)%3] (write A_{s+1})
    char* bC = hbase + 1024 * 1024;    // buf[(s+2)%3] (clear-behind)

    char* aldsW4 = Alds + wave * 4096;        // this wave's 4 LDS rows
    const int frow = wave * 4 + hi;           // FC row 0..15
    const int fr7  = frow & 7;
    const int swz  = l15 & 7;

    __syncthreads();   // WfcLDS ready

    for (int s = 0; s <= TT; ++s) {
        if (s == TT && hs != 0) break;        // only hs==0 needs the final tiles

        #pragma unroll
        for (int sl = 0; sl < 2; ++sl) {
            const size_t ldOff = sl ? ldOff1 : ldOff0;
            const size_t stOff = sl ? stOff1 : stOff0;
            const int    tIdx  = sl ? (bt + 16) : bt;
            float* creg = sl ? cregB : cregA;

            // 1. poll+stage this slot's 16x512 tile: wave w loads rows w*4+j
            //    (lane-contiguous 16B, full 64B lines), retry pending rows.
            {
                char* base = bA + ldOff;
                unsigned pend = 0xFu;
                ull2 q0, q1, q2, q3;
                for (;;) {
                    if (pend & 1u) asm volatile("global_load_dwordx4 %0, %1, off sc0 sc1"             : "=v"(q0) : "v"(base) : "memory");
                    if (pend & 2u) asm volatile("global_load_dwordx4 %0, %1, off offset:1024 sc0 sc1" : "=v"(q1) : "v"(base) : "memory");
                    if (pend & 4u) asm volatile("global_load_dwordx4 %0, %1, off offset:2048 sc0 sc1" : "=v"(q2) : "v"(base) : "memory");
                    if (pend & 8u) asm volatile("global_load_dwordx4 %0, %1, off offset:3072 sc0 sc1" : "=v"(q3) : "v"(base) : "memory");
                    asm volatile("s_waitcnt vmcnt(0)" ::: "memory");
                    __builtin_amdgcn_sched_barrier(0);
#define ACCEPT(J, QQ)                                                          \
                    if ((pend & (1u << J)) && !has_sent2(QQ)) {                \
                        *(ull2*)(aldsW4 + J * 1024 +                           \
                                 ((lane ^ (((wave & 1) << 2) | J)) << 4)) = QQ;\
                        pend &= ~(1u << J);                                    \
                    }
                    ACCEPT(0, q0) ACCEPT(1, q1) ACCEPT(2, q2) ACCEPT(3, q3)
#undef ACCEPT
                    if (!pend) break;
                    __builtin_amdgcn_s_sleep(1);
                }
            }
            __syncthreads();   // full tile staged => group finished iter s-1

            // 2. clear-behind: sentinel my granule in buf[(s+2)%3]
            if (s < TT && doSt) {
                ull sv = SENT;
                asm volatile("global_store_dwordx2 %0, %1, off sc0 sc1"
                             :: "v"(bC + stOff), "v"(sv) : "memory");
            }

            // 3. FC: s==0 correction (all wgs) and/or y-output (hs==0)
            if (s == 0 || hs == 0) {
                float xacc = 0.f;
                const char* arow = Alds + frow * 1024;
                #pragma unroll
                for (int u = 0; u < 4; ++u) {
                    int cc = l15 * 4 + u;
                    bf16x8 v = *(const bf16x8*)(arow + ((cc ^ fr7) << 4));
                    const float* wv = WfcLDS + cc * 8;
                    #pragma unroll
                    for (int e = 0; e < 8; ++e) xacc += (float)v[e] * wv[e];
                }
                xacc += __shfl_xor(xacc, 1);
                xacc += __shfl_xor(xacc, 2);
                xacc += __shfl_xor(xacc, 4);
                xacc += __shfl_xor(xacc, 8);
                xacc += bfcv;
                if (l15 == 0) {
                    xls[frow] = xacc;
                    if (hs == 0 && s > 0)
                        out[(size_t)(tIdx * 16 + frow) * TT + (s - 1)] = xacc;
                }
            }

            if (s == TT) continue;            // epilogue: FC only, both slots

            // 4. MFMA: [16,512] @ [512, 32 B-rows]; A swizzled LDS, B regs
            f32x4 acc0 = (f32x4)0.f, acc1 = (f32x4)0.f;
            #pragma unroll
            for (int kk = 0; kk < 16; ++kk) {
                bf16x8 a0 = *(const bf16x8*)(Alds + l15 * 1024 +
                                             (((hi + 4 * kk) ^ swz) << 4));
                acc0 = __builtin_amdgcn_mfma_f32_16x16x32_bf16(a0, breg[0][kk], acc0, 0, 0, 0);
                acc1 = __builtin_amdgcn_mfma_f32_16x16x32_bf16(a0, breg[1][kk], acc1, 0, 0, 0);
            }

            if (s == 0) __syncthreads();      // xls visible for the correction

            // 5. pointwise: lo lanes own (rows hi*4+r, col jcol); one
            //    shfl_xor(8) per (nt,r) brings the partner gate (f / o).
            #pragma unroll
            for (int r = 0; r < 4; ++r) {
                float recv0 = __shfl_xor(acc0[r], 8);
                float recv1 = __shfl_xor(acc1[r], 8);
                if (lo) {
                    float xc = (s == 0) ? xls[hi * 4 + r] : 0.f;
                    float xi = acc0[r] + bI - xc * wI;
                    float xf = recv0   + bF - xc * wF;
                    float xg = acc1[r] + bG - xc * wG;
                    float xo = recv1   + bO - xc * wO;
                    float si = sigmoid_fast(xi), sf = sigmoid_fast(xf), so = sigmoid_fast(xo);
                    float tg = tanh_fast(xg);
                    float cn = sf * creg[r] + si * tg;
                    creg[r] = cn;
                    hrep[hi * 4 + r][jcol] = (bf16)(so * tanh_fast(cn));
                }
            }
            __syncthreads();   // hrep complete; Alds reads finished

            // 6. store A_{s+1} granule. vmcnt(0): my sentinel clear of this
            //    granule (iter s-1) drained before the data store issues.
            if (doSt) {
                ull val = *(const ull*)&hrep[srow][seg * 4];
                asm volatile(
                    "s_waitcnt vmcnt(0)\n\t"
                    "global_store_dwordx2 %0, %1, off sc0 sc1"
                    :: "v"(bB + stOff), "v"(val) : "memory");
            }
        }   // slot loop

        if (s == TT) break;                   // epilogue done (y[TT-1] emitted)

        // rotate buffers: (A,B,C) <- (B,C,A)
        char* t = bA; bA = bB; bB = bC; bC = t;
    }
}

extern "C" void kernel_launch(void* const* d_in, const int* in_sizes, int n_in,
                              void* d_out, int out_size, void* d_ws, size_t ws_size,
                              hipStream_t stream) {
    const float* h   = (const float*)d_in[0];
    const float* c   = (const float*)d_in[1];
    const float* Wih = (const float*)d_in[2];
    const float* Whh = (const float*)d_in[3];
    const float* bih = (const float*)d_in[4];
    const float* bhh = (const float*)d_in[5];
    const float* Wfc = (const float*)d_in[6];
    const float* bfc = (const float*)d_in[7];
    float* out = (float*)d_out;

    char* ws = (char*)d_ws;
    bf16*  WcT   = (bf16*)(ws + WT_OFF);
    float* biasC = (float*)(ws + BC_OFF);
    char*  hb    = ws + H0_OFF;

    prep_weights<<<2048, 256, 0, stream>>>(Whh, Wih, bih, bhh, Wfc, bfc, WcT, biasC);
    prep_state<<<1024, 256, 0, stream>>>(h, (bf16*)hb,
        (unsigned short*)(hb + 512 * 1024), (unsigned short*)(hb + 1024 * 1024));
    lstm_persist<<<256, 256, 0, stream>>>(WcT, biasC, Wih, Wfc, bfc, c, hb, out);
}

// Round 12
// 5124.561 us; speedup vs baseline: 13.0829x; 1.2110x over previous
//
#include <hip/hip_runtime.h>
#include <hip/hip_bf16.h>
#include <math.h>

#define BB 512
#define HH 512
#define TT 1024

typedef __bf16 bf16;
typedef __bf16 bf16x8 __attribute__((ext_vector_type(8)));
typedef float f32x4 __attribute__((ext_vector_type(4)));
typedef unsigned long long ull;
typedef ull ull2 __attribute__((ext_vector_type(2)));

#define SENT 0x7FC07FC07FC07FC0ULL   // 4x bf16 NaN — h = so*tanh(c) is never NaN

// ---------------- ws layout (bytes) ----------------
// WcT : [2048][512] bf16 @ 0      (2 MB)  folded: Whh + Wfc ⊗ Wih
// biasC: [2048] f32      @ 2 MB   (8 KB)
// hb0/1/2: [512][512] bf16 rotating h buffers (3 x 512 KB)
#define WT_OFF 0
#define BC_OFF (2*1024*1024)
#define H0_OFF (BC_OFF + 8192)

__global__ void prep_weights(const float* __restrict__ Whh, const float* __restrict__ Wih,
                             const float* __restrict__ bih, const float* __restrict__ bhh,
                             const float* __restrict__ Wfc, const float* __restrict__ bfc,
                             bf16* __restrict__ WcT, float* __restrict__ biasC) {
    int col = blockIdx.x;                 // 0..2047
    float wih = Wih[col];
    for (int k = threadIdx.x; k < HH; k += blockDim.x)
        WcT[col * HH + k] = (bf16)(Whh[col * HH + k] + Wfc[k] * wih);
    if (threadIdx.x == 0) biasC[col] = bih[col] + bhh[col] + bfc[0] * wih;
}

__global__ void prep_state(const float* __restrict__ h, bf16* __restrict__ h0buf,
                           unsigned short* __restrict__ h1buf,
                           unsigned short* __restrict__ h2buf) {
    int i = blockIdx.x * blockDim.x + threadIdx.x;
    if (i < BB * HH) {
        h0buf[i] = (bf16)h[i];
        h1buf[i] = 0x7FC0;    // sentinel
        h2buf[i] = 0x7FC0;
    }
}

__device__ __forceinline__ float tanh_fast(float x) {
    float ax = fabsf(x);
    float e = __expf(-2.f * ax);
    float r = (1.f - e) / (1.f + e);
    return copysignf(r, x);
}
__device__ __forceinline__ float sigmoid_fast(float x) {
    return 1.f / (1.f + __expf(-x));
}
__device__ __forceinline__ bool has_sent(ull v) {
    ull y = v ^ SENT;
    return ((y - 0x0001000100010001ULL) & ~y & 0x8000800080008000ULL) != 0ULL;
}
__device__ __forceinline__ bool has_sent2(ull2 v) {
    return has_sent(v.x) | has_sent(v.y);
}

// Persistent LSTM, round-9 protocol (NaN-sentinel, 3 rotating buffers,
// clear-behind, MALL-only sc0 sc1 exchange — the only validated inter-wg
// path; lane-contiguous 16B staging loads). Critical-path fixes this round:
//  (a) h-store issues WITHOUT a preceding vmcnt(0): the clear it ordered is
//      already drained by this step's staging-barrier vmcnt(0); the
//      same-step clear targets a different buffer (no ordering needed).
//  (b) y-FC is distributed round-robin (wg hs emits y at steps s%16==hs) and
//      runs AFTER the h-store on wave-local LDS rows — uniform work, off the
//      producer->consumer path (the old always-hs==0 FC made those wgs the
//      per-step group straggler).
__global__ __launch_bounds__(256, 1) void lstm_persist(
    const bf16* __restrict__ WcT,     // [2048][512] bf16 (folded)
    const float* __restrict__ biasC,  // [2048]
    const float* __restrict__ Wih,    // [2048]
    const float* __restrict__ Wfc,    // [512]
    const float* __restrict__ bfc,    // [1]
    const float* __restrict__ c0,     // [512*512] f32
    char* __restrict__ hbase,         // 3 x 512KB rotating buffers
    float* __restrict__ out)          // [512][1024]
{
    __shared__ __align__(16) bf16 Alds[32 * 512];  // XOR-swizzled h tile (32 KB)
    __shared__ float xls[32];                      // step-0 correction per row
    __shared__ float WfcLDS[512];
    __shared__ bf16 hrep[32][40];                  // h repack for coalesced stores

    const int tid  = threadIdx.x;
    const int wave = tid >> 6;
    const int lane = tid & 63;
    const int l15  = lane & 15;
    const int hi   = lane >> 4;
    // group mapping (XCD swizzle is perf-only; correctness is placement-free)
    const int xcd = blockIdx.x & 7;
    const int ii  = blockIdx.x >> 3;
    const int bt  = xcd * 2 + (ii & 1);       // 0..15
    const int hs  = ii >> 1;                  // 0..15

    WfcLDS[tid] = Wfc[tid];
    WfcLDS[tid + 256] = Wfc[tid + 256];

    // ---- preload folded weights into registers ----
    bf16x8 breg[2][16];
    float biasr[2], wihr[2];
    #pragma unroll
    for (int nt = 0; nt < 2; ++nt) {
        int gcol = (nt * 2 + (l15 >> 3)) * HH + hs * 32 + wave * 8 + (l15 & 7);
        const bf16* wp = WcT + (size_t)gcol * HH + hi * 8;
        #pragma unroll
        for (int kk = 0; kk < 16; ++kk)
            breg[nt][kk] = *(const bf16x8*)(wp + kk * 32);
        biasr[nt] = biasC[gcol];
        wihr[nt]  = Wih[gcol];
    }
    const bool lo = (l15 < 8);
    float p0 = __shfl_xor(biasr[0], 8), p1 = __shfl_xor(biasr[1], 8);
    const float bI = lo ? biasr[0] : p0, bF = lo ? p0 : biasr[0];
    const float bG = lo ? biasr[1] : p1, bO = lo ? p1 : biasr[1];
    p0 = __shfl_xor(wihr[0], 8); p1 = __shfl_xor(wihr[1], 8);
    const float wI = lo ? wihr[0] : p0, wF = lo ? p0 : wihr[0];
    const float wG = lo ? wihr[1] : p1, wO = lo ? p1 : wihr[1];

    const int mymt = lo ? 0 : 1;
    const int jcol = wave * 8 + (l15 & 7);    // col within slice (0..31)
    const int jloc = hs * 32 + jcol;
    float creg[4];
    #pragma unroll
    for (int r = 0; r < 4; ++r) {
        int brow = bt * 32 + mymt * 16 + hi * 4 + r;
        creg[r] = c0[(size_t)brow * HH + jloc];
    }
    const float bfcv = bfc[0];

    const int swz = l15 & 7;
    const int row = tid >> 3;                 // pointwise/store/FC row 0..31
    const int seg = tid & 7;
    const int r7  = row & 7;

    // load base (lane-contiguous): wave w covers rows w*8..w*8+8, lane reads
    // 16B at row*1024 + lane*16; rows j=0..3 via base, j=4..7 via base+4096.
    const size_t grp = ((size_t)(bt * 32 + wave * 8)) * 1024 + (size_t)lane * 16;
    // store addr: 8B at (bt*32+row)*1024 + hs*64 + seg*8
    const size_t sto = ((size_t)(bt * 32 + row)) * 1024 + (size_t)hs * 64 + (size_t)seg * 8;

    char* laA = hbase + grp;                  // buf[s%3]     (read A_s)
    char* laB = hbase + 512 * 1024 + grp;
    char* laC = hbase + 1024 * 1024 + grp;
    char* stA = hbase + sto;
    char* stB = hbase + 512 * 1024 + sto;     // buf[(s+1)%3] (write A_{s+1})
    char* stC = hbase + 1024 * 1024 + sto;    // buf[(s+2)%3] (clear-behind)

    char* aldsW = (char*)Alds + wave * 8 * 1024;   // this wave's 8 LDS rows

    __syncthreads();   // WfcLDS ready

    for (int s = 0; s <= TT; ++s) {
        if (s == TT && hs != 0) break;      // only hs==0 needs the final tile

        // 1. stage A_s tile: per-row lane-contiguous 16B loads (MALL, sc0 sc1),
        //    poll until non-sentinel; re-issue only pending rows.
        {
            char* blo = laA;
            char* bhi = laA + 4096;
            unsigned pend = 0xFFu;
            ull2 q0, q1, q2, q3, q4, q5, q6, q7;
            for (;;) {
                if (pend & 0x01u) asm volatile("global_load_dwordx4 %0, %1, off sc0 sc1"             : "=v"(q0) : "v"(blo) : "memory");
                if (pend & 0x02u) asm volatile("global_load_dwordx4 %0, %1, off offset:1024 sc0 sc1" : "=v"(q1) : "v"(blo) : "memory");
                if (pend & 0x04u) asm volatile("global_load_dwordx4 %0, %1, off offset:2048 sc0 sc1" : "=v"(q2) : "v"(blo) : "memory");
                if (pend & 0x08u) asm volatile("global_load_dwordx4 %0, %1, off offset:3072 sc0 sc1" : "=v"(q3) : "v"(blo) : "memory");
                if (pend & 0x10u) asm volatile("global_load_dwordx4 %0, %1, off sc0 sc1"             : "=v"(q4) : "v"(bhi) : "memory");
                if (pend & 0x20u) asm volatile("global_load_dwordx4 %0, %1, off offset:1024 sc0 sc1" : "=v"(q5) : "v"(bhi) : "memory");
                if (pend & 0x40u) asm volatile("global_load_dwordx4 %0, %1, off offset:2048 sc0 sc1" : "=v"(q6) : "v"(bhi) : "memory");
                if (pend & 0x80u) asm volatile("global_load_dwordx4 %0, %1, off offset:3072 sc0 sc1" : "=v"(q7) : "v"(bhi) : "memory");
                asm volatile("s_waitcnt vmcnt(0)" ::: "memory");
                __builtin_amdgcn_sched_barrier(0);
#define ACCEPT(J, QQ)                                                          \
                if ((pend & (1u << J)) && !has_sent2(QQ)) {                    \
                    *(ull2*)(aldsW + J * 1024 + ((lane ^ J) << 4)) = QQ;       \
                    pend &= ~(1u << J);                                        \
                }
                ACCEPT(0, q0) ACCEPT(1, q1) ACCEPT(2, q2) ACCEPT(3, q3)
                ACCEPT(4, q4) ACCEPT(5, q5) ACCEPT(6, q6) ACCEPT(7, q7)
#undef ACCEPT
                if (pend == 0) break;
                __builtin_amdgcn_s_sleep(1);
            }
        }
        __syncthreads();   // full A_s staged => whole group finished iter s-1
                           // (implicit vmcnt(0) drain: all prior clears/stores
                           //  of every thread are at the MALL past this point)

        // 2. clear-behind: sentinel my granule in buf[(s+2)%3]
        {
            ull sv = SENT;
            asm volatile("global_store_dwordx2 %0, %1, off sc0 sc1"
                         :: "v"(stC), "v"(sv) : "memory");
        }

        // 3a. step-0 correction FC (all wgs): xls = FC(h_0) per row
        if (s == 0) {
            float xacc = 0.f;
            const bf16* arow = Alds + row * 512;
            #pragma unroll
            for (int u = 0; u < 8; ++u) {
                int cc = seg * 8 + u;
                bf16x8 v = *(const bf16x8*)(arow + ((cc ^ r7) << 3));
                const float* wv = WfcLDS + cc * 8;
                #pragma unroll
                for (int e = 0; e < 8; ++e) xacc += (float)v[e] * wv[e];
            }
            xacc += __shfl_xor(xacc, 1);
            xacc += __shfl_xor(xacc, 2);
            xacc += __shfl_xor(xacc, 4);
            if (seg == 0) xls[row] = xacc + bfcv;
        }

        // 3b. epilogue: y[:, TT-1] = FC(h_TT) (only hs==0 wgs reach here)
        if (s == TT) {
            float xacc = 0.f;
            const bf16* arow = Alds + row * 512;
            #pragma unroll
            for (int u = 0; u < 8; ++u) {
                int cc = seg * 8 + u;
                bf16x8 v = *(const bf16x8*)(arow + ((cc ^ r7) << 3));
                const float* wv = WfcLDS + cc * 8;
                #pragma unroll
                for (int e = 0; e < 8; ++e) xacc += (float)v[e] * wv[e];
            }
            xacc += __shfl_xor(xacc, 1);
            xacc += __shfl_xor(xacc, 2);
            xacc += __shfl_xor(xacc, 4);
            if (seg == 0)
                out[((size_t)(bt * 32 + row)) * TT + (TT - 1)] = xacc + bfcv;
            break;
        }

        // 4. MFMA: [32,512] @ [512, 32 B-rows]; A from swizzled LDS, B from regs
        f32x4 acc[2][2];
        #pragma unroll
        for (int i = 0; i < 2; ++i)
            #pragma unroll
            for (int j = 0; j < 2; ++j) acc[i][j] = (f32x4)0.f;

        #pragma unroll
        for (int kk = 0; kk < 16; ++kk) {
            int ch = ((hi + 4 * kk) ^ swz) << 3;
            bf16x8 a0 = *(const bf16x8*)(Alds + l15 * 512 + ch);
            bf16x8 a1 = *(const bf16x8*)(Alds + (l15 + 16) * 512 + ch);
            acc[0][0] = __builtin_amdgcn_mfma_f32_16x16x32_bf16(a0, breg[0][kk], acc[0][0], 0, 0, 0);
            acc[0][1] = __builtin_amdgcn_mfma_f32_16x16x32_bf16(a0, breg[1][kk], acc[0][1], 0, 0, 0);
            acc[1][0] = __builtin_amdgcn_mfma_f32_16x16x32_bf16(a1, breg[0][kk], acc[1][0], 0, 0, 0);
            acc[1][1] = __builtin_amdgcn_mfma_f32_16x16x32_bf16(a1, breg[1][kk], acc[1][1], 0, 0, 0);
        }

        if (s == 0) __syncthreads();   // xls visible for the correction

        // 5. pointwise cell update (folded weights include x-feedback;
        //    s==0 subtracts the x0c*Wih correction since x_0 = 0)
        #pragma unroll
        for (int r = 0; r < 4; ++r) {
            float send0 = lo ? acc[1][0][r] : acc[0][0][r];
            float send1 = lo ? acc[1][1][r] : acc[0][1][r];
            float recv0 = __shfl_xor(send0, 8);
            float recv1 = __shfl_xor(send1, 8);
            float own0  = lo ? acc[0][0][r] : acc[1][0][r];
            float own1  = lo ? acc[0][1][r] : acc[1][1][r];
            int  lrow = mymt * 16 + hi * 4 + r;
            float xc = (s == 0) ? xls[lrow] : 0.f;
            float xi = (lo ? own0 : recv0) + bI - xc * wI;
            float xf = (lo ? recv0 : own0) + bF - xc * wF;
            float xg = (lo ? own1 : recv1) + bG - xc * wG;
            float xo = (lo ? recv1 : own1) + bO - xc * wO;
            float si = sigmoid_fast(xi), sf = sigmoid_fast(xf), so = sigmoid_fast(xo);
            float tg = tanh_fast(xg);
            float cn = sf * creg[r] + si * tg;
            creg[r] = cn;
            hrep[lrow][jcol] = (bf16)(so * tanh_fast(cn));
        }
        __syncthreads();   // hrep complete; Alds reads finished

        // 6. store A_{s+1} granule IMMEDIATELY (no vmcnt: the clear of this
        //    buffer, issued at step s-1, was drained by this step's staging
        //    barrier; the same-step clear targets a different buffer).
        {
            ull val = *(const ull*)&hrep[row][seg * 4];
            asm volatile("global_store_dwordx2 %0, %1, off sc0 sc1"
                         :: "v"(stB), "v"(val) : "memory");
        }

        // 7. y-output FC, round-robin: wg hs emits y[:, s-1] when s%16==hs.
        //    Runs AFTER the store, on wave-local LDS rows (no barrier needed).
        if (s > 0 && (s & 15) == hs) {
            float xacc = 0.f;
            const bf16* arow = Alds + row * 512;
            #pragma unroll
            for (int u = 0; u < 8; ++u) {
                int cc = seg * 8 + u;
                bf16x8 v = *(const bf16x8*)(arow + ((cc ^ r7) << 3));
                const float* wv = WfcLDS + cc * 8;
                #pragma unroll
                for (int e = 0; e < 8; ++e) xacc += (float)v[e] * wv[e];
            }
            xacc += __shfl_xor(xacc, 1);
            xacc += __shfl_xor(xacc, 2);
            xacc += __shfl_xor(xacc, 4);
            if (seg == 0)
                out[((size_t)(bt * 32 + row)) * TT + (s - 1)] = xacc + bfcv;
        }

        // rotate buffers: (A,B,C) <- (B,C,A)
        char* t;
        t = laA; laA = laB; laB = laC; laC = t;
        t = stA; stA = stB; stB = stC; stC = t;
    }
}

extern "C" void kernel_launch(void* const* d_in, const int* in_sizes, int n_in,
                              void* d_out, int out_size, void* d_ws, size_t ws_size,
                              hipStream_t stream) {
    const float* h   = (const float*)d_in[0];
    const float* c   = (const float*)d_in[1];
    const float* Wih = (const float*)d_in[2];
    const float* Whh = (const float*)d_in[3];
    const float* bih = (const float*)d_in[4];
    const float* bhh = (const float*)d_in[5];
    const float* Wfc = (const float*)d_in[6];
    const float* bfc = (const float*)d_in[7];
    float* out = (float*)d_out;

    char* ws = (char*)d_ws;
    bf16*  WcT   = (bf16*)(ws + WT_OFF);
    float* biasC = (float*)(ws + BC_OFF);
    char*  hb    = ws + H0_OFF;

    prep_weights<<<2048, 256, 0, stream>>>(Whh, Wih, bih, bhh, Wfc, bfc, WcT, biasC);
    prep_state<<<1024, 256, 0, stream>>>(h, (bf16*)hb,
        (unsigned short*)(hb + 512 * 1024), (unsigned short*)(hb + 1024 * 1024));
    lstm_persist<<<256, 256, 0, stream>>>(WcT, biasC, Wih, Wfc, bfc, c, hb, out);
}